// Round 10
// baseline (3877.669 us; speedup 1.0000x reference)
//
#include <hip/hip_runtime.h>
#include <stdint.h>

// FPS, two-batch pipelined persistent kernel (lean). B=32, N=131072, S=1024.
// 256 blocks x 512 threads; block = (pair, chunk): chunk c (0..15) of batches
// bA=pair, bB=pair+16. While batch A's rendezvous is in flight, the block
// updates batch B (and vice versa) -> LLC visibility latency hidden under
// ~0.85us of independent compute. Lean payload (R9 post-mortem): slot = ONE
// u64 key, coords re-gathered from global (wave-uniform, L2-hot), inner loop
// identical to R6's (absmax=0 pedigree).

#define NB        32
#define NPTS      131072
#define NSAMP     1024
#define NCH       16
#define THREADS   512
#define WAVES     8
#define PPT       16          // NPTS / (NCH * THREADS)
#define CHUNK_PTS 8192        // NPTS / NCH
#define BIGF      1e10f
#define SEQ_MASK  0x7FFFull   // s <= 1023; 0xAA poison seq = 0x2AAA never matches

// key: [dist_bits:32][NPTS-1-idx:17][seq:15] -> u64 max == (dist desc, idx asc)
// Overwrite safety: a block writing parity slot for round s+2 must have passed
// poll(s+1), which requires all blocks posted s+1, which requires all consumed
// s -> no poller of round s can see the s+2 overwrite. bc##X reads/writes are
// separated by >=3 barriers from the next overwrite.

#define UPDATE_PHASE(X)                                                        \
  {                                                                            \
    const float px = bc##X[0], py = bc##X[1], pz = bc##X[2];                   \
    float bv = -1.0f; int bi = 0;                                              \
    _Pragma("unroll")                                                          \
    for (int i = 0; i < PPT; ++i) {                                            \
      const float dx = x##X[i] - px;                                           \
      const float dy = y##X[i] - py;                                           \
      const float dz = z##X[i] - pz;                                           \
      float dd = dx * dx; dd = dd + dy * dy; dd = dd + dz * dz;                \
      const float nd = fminf(d##X[i], dd); d##X[i] = nd;                       \
      if (nd > bv) { bv = nd; bi = c * CHUNK_PTS + i * THREADS + t; }          \
    }                                                                          \
    _Pragma("unroll")                                                          \
    for (int off = 32; off > 0; off >>= 1) {                                   \
      const float ov = __shfl_xor(bv, off);                                    \
      const int   oi = __shfl_xor(bi, off);                                    \
      if (ov > bv || (ov == bv && oi < bi)) { bv = ov; bi = oi; }              \
    }                                                                          \
    if (lane == 0)                                                             \
      wk##X[w] = ((unsigned long long)__float_as_uint(bv) << 32)               \
               | ((unsigned long long)(NPTS - 1 - bi) << 15);                  \
  }

#define POST_HALF(X, sPost)                                                    \
  {                                                                            \
    unsigned long long k = (lane < WAVES) ? wk##X[lane] : 0ull;                \
    _Pragma("unroll")                                                          \
    for (int off = 1; off < WAVES; off <<= 1) {                                \
      const unsigned long long o = __shfl_xor(k, off);                         \
      if (o > k) k = o;                                                        \
    }                                                                          \
    if (lane == 0) {                                                           \
      unsigned long long* sp = slots +                                         \
          (((size_t)((sPost) & 1) * NB + b##X) * NCH + c);                     \
      __hip_atomic_store(sp, k | (unsigned long long)(sPost),                  \
                         __ATOMIC_RELAXED, __HIP_MEMORY_SCOPE_AGENT);          \
    }                                                                          \
  }

#define POLL_HALF(Y, sPoll)                                                    \
  {                                                                            \
    unsigned long long pk = 0;                                                 \
    const unsigned long long sq = (unsigned long long)(sPoll);                 \
    if (lane < NCH) {                                                          \
      unsigned long long* sp = slots +                                         \
          (((size_t)((sPoll) & 1) * NB + b##Y) * NCH + lane);                  \
      do {                                                                     \
        pk = __hip_atomic_load(sp, __ATOMIC_RELAXED, __HIP_MEMORY_SCOPE_AGENT);\
      } while ((pk & SEQ_MASK) != sq);                                         \
    }                                                                          \
    _Pragma("unroll")                                                          \
    for (int off = 1; off < NCH; off <<= 1) {                                  \
      const unsigned long long o = __shfl_xor(pk, off);                        \
      if (o > pk) pk = o;                                                      \
    }                                                                          \
    if (lane == 0) {                                                           \
      const int widx = (NPTS - 1) - (int)((pk >> 15) & 0x1FFFF);               \
      const float* bp = pts + (size_t)b##Y * NPTS * 3;                         \
      const float gx = bp[3 * (size_t)widx + 0];                               \
      const float gy = bp[3 * (size_t)widx + 1];                               \
      const float gz = bp[3 * (size_t)widx + 2];                               \
      bc##Y[0] = gx; bc##Y[1] = gy; bc##Y[2] = gz;                             \
      if (c == 0) {                                                            \
        const size_t o_ = ((size_t)b##Y * NSAMP + (sPoll)) * 3;                \
        out[o_ + 0] = gx; out[o_ + 1] = gy; out[o_ + 2] = gz;                  \
      }                                                                        \
    }                                                                          \
  }

__global__ __launch_bounds__(THREADS, 2)   // 256-VGPR cap; grid=256 -> 1 block/CU guaranteed
void fps_kernel(const float* __restrict__ pts,
                float* __restrict__ out,
                unsigned long long* __restrict__ slots)
{
    #pragma clang fp contract(off)   // match XLA's un-contracted (dx^2+dy^2)+dz^2 (absmax=0 R2/R6-R9)

    const int pair = blockIdx.x & 15;      // blockIdx%8 == pair%8 -> pair's 16 blocks share an XCD
    const int c    = blockIdx.x >> 4;      // chunk 0..15
    const int bA   = pair, bB = pair + 16;
    const int t    = threadIdx.x;
    const int w    = t >> 6;
    const int lane = t & 63;

    __shared__ unsigned long long wkA[WAVES], wkB[WAVES];
    __shared__ float bcA[3], bcB[3];

    const float* pA = pts + (size_t)bA * NPTS * 3;
    const float* pB = pts + (size_t)bB * NPTS * 3;

    // Per-thread state: 2 batches x (3x16 coords + 16 dist) = 128 floats.
    float xA[PPT], yA[PPT], zA[PPT], dA[PPT];
    float xB[PPT], yB[PPT], zB[PPT], dB[PPT];
    #pragma unroll
    for (int i = 0; i < PPT; ++i) {
        const int n = c * CHUNK_PTS + i * THREADS + t;   // lane-consecutive -> coalesced
        xA[i] = pA[3*n+0]; yA[i] = pA[3*n+1]; zA[i] = pA[3*n+2]; dA[i] = BIGF;
        xB[i] = pB[3*n+0]; yB[i] = pB[3*n+1]; zB[i] = pB[3*n+2]; dB[i] = BIGF;
    }

    // Round 0 winner = point 0 for both batches.
    if (t == 0) {
        bcA[0] = pA[0]; bcA[1] = pA[1]; bcA[2] = pA[2];
        bcB[0] = pB[0]; bcB[1] = pB[1]; bcB[2] = pB[2];
    }
    if (c == 0 && t == 0) {
        out[(size_t)bA*NSAMP*3+0] = pA[0]; out[(size_t)bA*NSAMP*3+1] = pA[1]; out[(size_t)bA*NSAMP*3+2] = pA[2];
        out[(size_t)bB*NSAMP*3+0] = pB[0]; out[(size_t)bB*NSAMP*3+1] = pB[1]; out[(size_t)bB*NSAMP*3+2] = pB[2];
    }
    __syncthreads();

    // Prologue: candidates A(1), posted; nothing to poll yet.
    UPDATE_PHASE(A)
    __syncthreads();
    if (w == 0) { POST_HALF(A, 1) }
    // next phase touches only B-state; its trailing barrier orders everything.

    // Steady state: iteration s completes round s for BOTH batches.
    for (int s = 1; s < NSAMP; ++s) {
        UPDATE_PHASE(B)                       // uses winner B(s-1)
        __syncthreads();
        if      (w == 0) { POST_HALF(B, s) }  // candidates B(s)
        else if (w == 1) { POLL_HALF(A, s) }  // resolve winner A(s) -> bcA, out
        __syncthreads();

        if (s < NSAMP - 1) {
            UPDATE_PHASE(A)                        // uses winner A(s)
            __syncthreads();
            if      (w == 0) { POST_HALF(A, s + 1) }
            else if (w == 1) { POLL_HALF(B, s) }   // winner B(s) -> bcB, out
            __syncthreads();
        } else {
            if (w == 1) { POLL_HALF(B, s) }        // final B output
            __syncthreads();
        }
    }
}

extern "C" void kernel_launch(void* const* d_in, const int* in_sizes, int n_in,
                              void* d_out, int out_size, void* d_ws, size_t ws_size,
                              hipStream_t stream)
{
    const float* pts = (const float*)d_in[0];
    float* out = (float*)d_out;

    // slots[2][NB][NCH] u64 = 8 KiB. No init needed: 0xAA poison seq (0x2AAA)
    // never equals any round s <= 1023.
    unsigned long long* slots = (unsigned long long*)d_ws;

    fps_kernel<<<dim3(256), dim3(THREADS), 0, stream>>>(pts, out, slots);
}